// Round 2
// baseline (1138.714 us; speedup 1.0000x reference)
//
#include <hip/hip_runtime.h>

#define BETA2 25.0f
#define EPS 1e-9f
#define UNROLL 8
#define BLOCK 256
#define TILE (BLOCK * UNROLL)   // float4s per block per array

// d_ws layout: 3 x unsigned int counters [tp, fp, fn]

__global__ void fbeta_zero(unsigned int* counts) {
    if (threadIdx.x < 3) counts[threadIdx.x] = 0u;
}

__device__ __forceinline__ void acc3(float t, float l, int& tp, int& fp, int& fn) {
    int tn = (t != 0.0f), ln = (l != 0.0f);
    tp += tn & ln;
    fp += tn & (ln ^ 1);
    fn += (tn ^ 1) & ln;
}

__global__ void __launch_bounds__(BLOCK) fbeta_count(const float4* __restrict__ t4,
                                                     const float4* __restrict__ l4,
                                                     unsigned int* __restrict__ counts,
                                                     int n4) {
    const int tileStart = blockIdx.x * TILE;
    int tp = 0, fp = 0, fn = 0;

    if (tileStart + TILE <= n4) {
        // Fast path: issue all 16 loads before consuming (max MLP).
        float4 tv[UNROLL], lv[UNROLL];
        #pragma unroll
        for (int k = 0; k < UNROLL; ++k)
            tv[k] = t4[tileStart + k * BLOCK + threadIdx.x];
        #pragma unroll
        for (int k = 0; k < UNROLL; ++k)
            lv[k] = l4[tileStart + k * BLOCK + threadIdx.x];
        #pragma unroll
        for (int k = 0; k < UNROLL; ++k) {
            acc3(tv[k].x, lv[k].x, tp, fp, fn);
            acc3(tv[k].y, lv[k].y, tp, fp, fn);
            acc3(tv[k].z, lv[k].z, tp, fp, fn);
            acc3(tv[k].w, lv[k].w, tp, fp, fn);
        }
    } else {
        // Tail path (not hit at N=2^26, kept for generality).
        for (int i = tileStart + threadIdx.x; i < n4; i += BLOCK) {
            float4 tv = t4[i];
            float4 lv = l4[i];
            acc3(tv.x, lv.x, tp, fp, fn);
            acc3(tv.y, lv.y, tp, fp, fn);
            acc3(tv.z, lv.z, tp, fp, fn);
            acc3(tv.w, lv.w, tp, fp, fn);
        }
    }

    // wave-64 reduction
    #pragma unroll
    for (int off = 32; off > 0; off >>= 1) {
        tp += __shfl_down(tp, off, 64);
        fp += __shfl_down(fp, off, 64);
        fn += __shfl_down(fn, off, 64);
    }
    if ((threadIdx.x & 63) == 0) {
        atomicAdd(&counts[0], (unsigned int)tp);
        atomicAdd(&counts[1], (unsigned int)fp);
        atomicAdd(&counts[2], (unsigned int)fn);
    }
}

__global__ void fbeta_final(const unsigned int* __restrict__ counts,
                            float* __restrict__ out) {
    float tp = (float)counts[0] + EPS;
    float fp = (float)counts[1] + EPS;
    float fn = (float)counts[2] + EPS;
    float precision = tp / (tp + fp);
    float recall    = tp / (tp + fn);
    out[0] = (1.0f + BETA2) * (precision * recall) / (BETA2 * precision + recall);
}

extern "C" void kernel_launch(void* const* d_in, const int* in_sizes, int n_in,
                              void* d_out, int out_size, void* d_ws, size_t ws_size,
                              hipStream_t stream) {
    const float* targets = (const float*)d_in[0];
    const float* labels  = (const float*)d_in[1];
    float* out = (float*)d_out;
    unsigned int* counts = (unsigned int*)d_ws;

    const int n = in_sizes[0];      // 67108864
    const int n4 = n >> 2;          // 16777216 float4s
    const int grid = (n4 + TILE - 1) / TILE;   // 8192 blocks

    fbeta_zero<<<1, 64, 0, stream>>>(counts);
    fbeta_count<<<grid, BLOCK, 0, stream>>>((const float4*)targets,
                                            (const float4*)labels,
                                            counts, n4);
    fbeta_final<<<1, 1, 0, stream>>>(counts, out);
}

// Round 3
// 105.105 us; speedup vs baseline: 10.8341x; 10.8341x over previous
//
#include <hip/hip_runtime.h>

#define BETA2 25.0f
#define EPS 1e-9f
#define BLOCK 256
#define GRID 2048

// d_ws layout (SoA, uint): [GRID] tp partials | [GRID] fp partials | [GRID] fn partials

__device__ __forceinline__ void acc3(float t, float l, int& tp, int& fp, int& fn) {
    int tn = (t != 0.0f), ln = (l != 0.0f);
    tp += tn & ln;
    fp += tn & (ln ^ 1);
    fn += (tn ^ 1) & ln;
}

__global__ void __launch_bounds__(BLOCK) fbeta_count(const float4* __restrict__ t4,
                                                     const float4* __restrict__ l4,
                                                     unsigned int* __restrict__ partials,
                                                     int n4, int nblocks) {
    int tp = 0, fp = 0, fn = 0;
    const int stride = gridDim.x * blockDim.x;
    for (int i = blockIdx.x * blockDim.x + threadIdx.x; i < n4; i += stride) {
        float4 tv = t4[i];
        float4 lv = l4[i];
        acc3(tv.x, lv.x, tp, fp, fn);
        acc3(tv.y, lv.y, tp, fp, fn);
        acc3(tv.z, lv.z, tp, fp, fn);
        acc3(tv.w, lv.w, tp, fp, fn);
    }

    // wave-64 reduction
    #pragma unroll
    for (int off = 32; off > 0; off >>= 1) {
        tp += __shfl_down(tp, off, 64);
        fp += __shfl_down(fp, off, 64);
        fn += __shfl_down(fn, off, 64);
    }

    // cross-wave reduction in LDS, then ONE plain store set per block (no atomics)
    __shared__ int s[3][BLOCK / 64];
    const int wave = threadIdx.x >> 6;
    if ((threadIdx.x & 63) == 0) {
        s[0][wave] = tp;
        s[1][wave] = fp;
        s[2][wave] = fn;
    }
    __syncthreads();
    if (threadIdx.x == 0) {
        int btp = 0, bfp = 0, bfn = 0;
        #pragma unroll
        for (int w = 0; w < BLOCK / 64; ++w) {
            btp += s[0][w];
            bfp += s[1][w];
            bfn += s[2][w];
        }
        partials[blockIdx.x]               = (unsigned int)btp;
        partials[nblocks + blockIdx.x]     = (unsigned int)bfp;
        partials[2 * nblocks + blockIdx.x] = (unsigned int)bfn;
    }
}

__global__ void __launch_bounds__(BLOCK) fbeta_reduce(const unsigned int* __restrict__ partials,
                                                      float* __restrict__ out, int nblocks) {
    unsigned int tp = 0, fp = 0, fn = 0;
    for (int b = threadIdx.x; b < nblocks; b += BLOCK) {
        tp += partials[b];
        fp += partials[nblocks + b];
        fn += partials[2 * nblocks + b];
    }
    #pragma unroll
    for (int off = 32; off > 0; off >>= 1) {
        tp += __shfl_down(tp, off, 64);
        fp += __shfl_down(fp, off, 64);
        fn += __shfl_down(fn, off, 64);
    }
    __shared__ unsigned int s[3][BLOCK / 64];
    const int wave = threadIdx.x >> 6;
    if ((threadIdx.x & 63) == 0) {
        s[0][wave] = tp;
        s[1][wave] = fp;
        s[2][wave] = fn;
    }
    __syncthreads();
    if (threadIdx.x == 0) {
        float ftp = 0.f, ffp = 0.f, ffn = 0.f;
        #pragma unroll
        for (int w = 0; w < BLOCK / 64; ++w) {
            ftp += (float)s[0][w];
            ffp += (float)s[1][w];
            ffn += (float)s[2][w];
        }
        ftp += EPS; ffp += EPS; ffn += EPS;
        float precision = ftp / (ftp + ffp);
        float recall    = ftp / (ftp + ffn);
        out[0] = (1.0f + BETA2) * (precision * recall) / (BETA2 * precision + recall);
    }
}

extern "C" void kernel_launch(void* const* d_in, const int* in_sizes, int n_in,
                              void* d_out, int out_size, void* d_ws, size_t ws_size,
                              hipStream_t stream) {
    const float* targets = (const float*)d_in[0];
    const float* labels  = (const float*)d_in[1];
    float* out = (float*)d_out;
    unsigned int* partials = (unsigned int*)d_ws;

    const int n = in_sizes[0];      // 67108864
    const int n4 = n >> 2;          // float4 count

    fbeta_count<<<GRID, BLOCK, 0, stream>>>((const float4*)targets,
                                            (const float4*)labels,
                                            partials, n4, GRID);
    fbeta_reduce<<<1, BLOCK, 0, stream>>>(partials, out, GRID);
}

// Round 4
// 94.878 us; speedup vs baseline: 12.0019x; 1.1078x over previous
//
#include <hip/hip_runtime.h>

#define BETA2 25.0f
#define EPS 1e-9f
#define BLOCK 256
#define GRID 2048
#define UN 4
#define CHUNK (BLOCK * UN)   // float4s consumed per array per block per iteration

// d_ws layout (SoA, uint): [GRID] tp partials | [GRID] fp partials | [GRID] fn partials

__device__ __forceinline__ void acc3(float t, float l, int& tp, int& fp, int& fn) {
    int tn = (t != 0.0f), ln = (l != 0.0f);
    tp += tn & ln;
    fp += tn & (ln ^ 1);
    fn += (tn ^ 1) & ln;
}

__global__ void __launch_bounds__(BLOCK) fbeta_count(const float4* __restrict__ t4,
                                                     const float4* __restrict__ l4,
                                                     unsigned int* __restrict__ partials,
                                                     int n4, int nblocks) {
    int tp = 0, fp = 0, fn = 0;
    const int nchunks = n4 / CHUNK;          // 16384 at N=2^26 (exact)

    for (int c = blockIdx.x; c < nchunks; c += gridDim.x) {
        const int base = c * CHUNK + threadIdx.x;
        float4 tv[UN], lv[UN];
        #pragma unroll
        for (int k = 0; k < UN; ++k) tv[k] = t4[base + k * BLOCK];
        #pragma unroll
        for (int k = 0; k < UN; ++k) lv[k] = l4[base + k * BLOCK];
        #pragma unroll
        for (int k = 0; k < UN; ++k) {
            acc3(tv[k].x, lv[k].x, tp, fp, fn);
            acc3(tv[k].y, lv[k].y, tp, fp, fn);
            acc3(tv[k].z, lv[k].z, tp, fp, fn);
            acc3(tv[k].w, lv[k].w, tp, fp, fn);
        }
    }

    // Tail (not hit at N=2^26, kept for generality).
    for (int i = nchunks * CHUNK + blockIdx.x * BLOCK + threadIdx.x; i < n4;
         i += gridDim.x * BLOCK) {
        float4 tv = t4[i];
        float4 lv = l4[i];
        acc3(tv.x, lv.x, tp, fp, fn);
        acc3(tv.y, lv.y, tp, fp, fn);
        acc3(tv.z, lv.z, tp, fp, fn);
        acc3(tv.w, lv.w, tp, fp, fn);
    }

    // wave-64 reduction
    #pragma unroll
    for (int off = 32; off > 0; off >>= 1) {
        tp += __shfl_down(tp, off, 64);
        fp += __shfl_down(fp, off, 64);
        fn += __shfl_down(fn, off, 64);
    }

    // cross-wave reduction in LDS, then plain per-block stores (no atomics)
    __shared__ int s[3][BLOCK / 64];
    const int wave = threadIdx.x >> 6;
    if ((threadIdx.x & 63) == 0) {
        s[0][wave] = tp;
        s[1][wave] = fp;
        s[2][wave] = fn;
    }
    __syncthreads();
    if (threadIdx.x == 0) {
        int btp = 0, bfp = 0, bfn = 0;
        #pragma unroll
        for (int w = 0; w < BLOCK / 64; ++w) {
            btp += s[0][w];
            bfp += s[1][w];
            bfn += s[2][w];
        }
        partials[blockIdx.x]               = (unsigned int)btp;
        partials[nblocks + blockIdx.x]     = (unsigned int)bfp;
        partials[2 * nblocks + blockIdx.x] = (unsigned int)bfn;
    }
}

__global__ void __launch_bounds__(BLOCK) fbeta_reduce(const unsigned int* __restrict__ partials,
                                                      float* __restrict__ out, int nblocks) {
    unsigned int tp = 0, fp = 0, fn = 0;
    for (int b = threadIdx.x; b < nblocks; b += BLOCK) {
        tp += partials[b];
        fp += partials[nblocks + b];
        fn += partials[2 * nblocks + b];
    }
    #pragma unroll
    for (int off = 32; off > 0; off >>= 1) {
        tp += __shfl_down(tp, off, 64);
        fp += __shfl_down(fp, off, 64);
        fn += __shfl_down(fn, off, 64);
    }
    __shared__ unsigned int s[3][BLOCK / 64];
    const int wave = threadIdx.x >> 6;
    if ((threadIdx.x & 63) == 0) {
        s[0][wave] = tp;
        s[1][wave] = fp;
        s[2][wave] = fn;
    }
    __syncthreads();
    if (threadIdx.x == 0) {
        float ftp = 0.f, ffp = 0.f, ffn = 0.f;
        #pragma unroll
        for (int w = 0; w < BLOCK / 64; ++w) {
            ftp += (float)s[0][w];
            ffp += (float)s[1][w];
            ffn += (float)s[2][w];
        }
        ftp += EPS; ffp += EPS; ffn += EPS;
        float precision = ftp / (ftp + ffp);
        float recall    = ftp / (ftp + ffn);
        out[0] = (1.0f + BETA2) * (precision * recall) / (BETA2 * precision + recall);
    }
}

extern "C" void kernel_launch(void* const* d_in, const int* in_sizes, int n_in,
                              void* d_out, int out_size, void* d_ws, size_t ws_size,
                              hipStream_t stream) {
    const float* targets = (const float*)d_in[0];
    const float* labels  = (const float*)d_in[1];
    float* out = (float*)d_out;
    unsigned int* partials = (unsigned int*)d_ws;

    const int n = in_sizes[0];      // 67108864
    const int n4 = n >> 2;          // float4 count

    fbeta_count<<<GRID, BLOCK, 0, stream>>>((const float4*)targets,
                                            (const float4*)labels,
                                            partials, n4, GRID);
    fbeta_reduce<<<1, BLOCK, 0, stream>>>(partials, out, GRID);
}